// Round 13
// baseline (100.294 us; speedup 1.0000x reference)
//
#include <hip/hip_runtime.h>

#define NEG_SLOPE_F 0.2f

static constexpr int Nn = 4096;   // nodes
static constexpr int Tt = 3;      // edge types
static constexpr int Dd = 16;     // emb dim
static constexpr int Hh = 4;      // heads
static constexpr int CAP = 256;   // max distinct neighbors per row (E[deg]≈96)
static constexpr int ROWS = 32;   // rows per block
static constexpr int NBLK = Nn / ROWS;  // 128 blocks
static constexpr int WPT = 128;   // bitmap words per (row,type): 4096/32

__device__ __forceinline__ float waveMax(float v) {
#pragma unroll
  for (int m = 1; m < 64; m <<= 1) v = fmaxf(v, __shfl_xor(v, m));
  return v;
}
__device__ __forceinline__ float waveSum(float v) {
#pragma unroll
  for (int m = 1; m < 64; m <<= 1) v += __shfl_xor(v, m);
  return v;
}

// Single kernel, zero cross-block dependencies:
//   clear LDS bitmaps -> brute-scan the full edge list for this block's 32
//   rows (LDS atomicOr dedup, order-free -> deterministic) -> per-wave
//   extraction + analytic sparse softmax over the implicit 4096-j row.
__global__ void __launch_bounds__(256) fused_kernel(
    const float* __restrict__ scores, const float* __restrict__ emb,
    const float* __restrict__ attw, const int* __restrict__ el, int E,
    float* __restrict__ out) {
  __shared__ unsigned int bm[ROWS][Tt * WPT];  // 48 KB
  __shared__ unsigned short lst[4][CAP];       // 2 KB, wave-private slices
  __shared__ float pvs[16];                    // c[h][t] (12) + Ssum
  __shared__ float rb[4];

  int tid = threadIdx.x;
  int wid = tid >> 6, lane = tid & 63;
  int R0 = blockIdx.x * ROWS;

  // ---- clear the block's private bitmap ----
  unsigned int* bmf = &bm[0][0];
  for (int q = tid; q < ROWS * Tt * WPT; q += 256) bmf[q] = 0u;

  // ---- block-local sum(scores) (redundant per block; 16 KB L2-hot) ----
  {
    float s = 0.f;
    for (int j = tid; j < Nn; j += 256) s += scores[j];
    s = waveSum(s);
    if (lane == 0) rb[wid] = s;
  }
  __syncthreads();  // bitmap cleared + rb ready
  if (tid == 0) pvs[12] = rb[0] + rb[1] + rb[2] + rb[3];
  if (tid < Hh * Tt) {
    int h = tid / Tt, t = tid % Tt;
    float c = 0.f;
#pragma unroll
    for (int d = 0; d < Dd; ++d)
      c += emb[t * Dd + d] * attw[h * (Dd + 2) + 1 + d];
    pvs[tid] = c;
  }

  // ---- brute scan of the full edge list (int4-vectorized, coalesced) ----
  int E4 = E >> 2;
  for (int t = 0; t < Tt; ++t) {
    const int4* s4 = (const int4*)(el + (size_t)(t * 2 + 0) * E);
    const int4* d4 = (const int4*)(el + (size_t)(t * 2 + 1) * E);
    for (int k = tid; k < E4; k += 256) {
      int4 a4 = s4[k], b4 = d4[k];
#pragma unroll
      for (int q = 0; q < 4; ++q) {
        unsigned int a =
            (unsigned int)(q == 0 ? a4.x : q == 1 ? a4.y : q == 2 ? a4.z : a4.w);
        unsigned int b =
            (unsigned int)(q == 0 ? b4.x : q == 1 ? b4.y : q == 2 ? b4.z : b4.w);
        unsigned int ra = a - (unsigned int)R0;
        if (ra < (unsigned int)ROWS)
          atomicOr(&bm[ra][t * WPT + (b >> 5)], 1u << (b & 31u));
        unsigned int rbx = b - (unsigned int)R0;
        if (rbx < (unsigned int)ROWS)
          atomicOr(&bm[rbx][t * WPT + (a >> 5)], 1u << (a & 31u));
      }
    }
    // generic tail (E % 4 != 0); no-op for E = 65536
    for (int e = E4 * 4 + tid; e < E; e += 256) {
      unsigned int a = (unsigned int)el[(size_t)(t * 2 + 0) * E + e];
      unsigned int b = (unsigned int)el[(size_t)(t * 2 + 1) * E + e];
      unsigned int ra = a - (unsigned int)R0;
      if (ra < (unsigned int)ROWS)
        atomicOr(&bm[ra][t * WPT + (b >> 5)], 1u << (b & 31u));
      unsigned int rbx = b - (unsigned int)R0;
      if (rbx < (unsigned int)ROWS)
        atomicOr(&bm[rbx][t * WPT + (a >> 5)], 1u << (a & 31u));
    }
  }
  __syncthreads();  // bitmap + pvs visible to row phase

  // ---- row phase: each wave processes 8 rows sequentially ----
  float wsrc[Hh], wtgt[Hh], c0[Hh], c1[Hh], c2[Hh];
#pragma unroll
  for (int h = 0; h < Hh; ++h) {
    wsrc[h] = attw[h * (Dd + 2) + 0];
    wtgt[h] = attw[h * (Dd + 2) + Dd + 1];
    c0[h] = pvs[h * 3 + 0];
    c1[h] = pvs[h * 3 + 1];
    c2[h] = pvs[h * 3 + 2];
  }
  float Ssum = pvs[12];

  constexpr int RPW = ROWS / 4;  // 8 rows per wave
  for (int rr = 0; rr < RPW; ++rr) {
    int lr = wid * RPW + rr;
    int i = R0 + lr;

    // canonical extraction (proven path), LDS-sourced
    unsigned int w[2][3];
#pragma unroll
    for (int p = 0; p < 2; ++p)
#pragma unroll
      for (int t = 0; t < 3; ++t) w[p][t] = bm[lr][t * WPT + p * 64 + lane];
    unsigned int orw[2];
    orw[0] = w[0][0] | w[0][1] | w[0][2];
    orw[1] = w[1][0] | w[1][1] | w[1][2];
    int c = __popc(orw[0]) + __popc(orw[1]);
    int off = c;
#pragma unroll
    for (int d = 1; d < 64; d <<= 1) {
      int tv = __shfl_up(off, d);
      if (lane >= d) off += tv;
    }
    int n = __shfl(off, 63);  // distinct neighbors of row i
    off -= c;                 // exclusive
    if (n > CAP) n = CAP;
    int idx = off;
#pragma unroll
    for (int p = 0; p < 2; ++p) {
      unsigned int o = orw[p];
      int jbase = (p * 64 + lane) * 32;
      while (o) {
        int b = __ffs(o) - 1;
        o &= o - 1;
        unsigned int m = ((w[p][0] >> b) & 1u) | (((w[p][1] >> b) & 1u) << 1) |
                         (((w[p][2] >> b) & 1u) << 2);
        if (idx < CAP) lst[wid][idx] = (unsigned short)((jbase + b) | (m << 12));
        ++idx;
      }
    }
    // lst[wid] produced+consumed by the same wave: no block barrier needed.

    float si = scores[i];
    constexpr int IT = CAP / 64;  // 4
    float lv[IT][Hh], sjv[IT];
    float mx[Hh];
#pragma unroll
    for (int h = 0; h < Hh; ++h) mx[h] = -INFINITY;
    float sedge = 0.f;

#pragma unroll
    for (int it = 0; it < IT; ++it) {
      if (it * 64 >= n) break;  // wave-uniform early-out
      int k = it * 64 + lane;
      bool act = k < n;
      unsigned int v = act ? (unsigned int)lst[wid][k] : 0u;
      int j = (int)(v & 0xFFFu);
      int m = act ? (int)(v >> 12) : 0;
      float sj = act ? scores[j] : 0.f;
      sjv[it] = sj;
      if (act) sedge += sj;
      float na = (float)__popc(m);
      float et0 = (m & 1) ? 1.f : 0.f;
      float et1 = (m & 2) ? 1.f : 0.f;
      float et2 = (m & 4) ? 1.f : 0.f;
#pragma unroll
      for (int h = 0; h < Hh; ++h) {
        float et = et0 * c0[h] + et1 * c1[h] + et2 * c2[h];
        float l = na * (wsrc[h] * si + wtgt[h] * sj) + et;
        l = (l >= 0.f) ? l : NEG_SLOPE_F * l;
        lv[it][h] = act ? l : -INFINITY;
        mx[h] = fmaxf(mx[h], lv[it][h]);
      }
    }

#pragma unroll
    for (int h = 0; h < Hh; ++h) {
      mx[h] = waveMax(mx[h]);
      if (n < Nn) mx[h] = fmaxf(mx[h], 0.f);  // non-edge logits are 0
    }

    float se[Hh], ss[Hh];
#pragma unroll
    for (int h = 0; h < Hh; ++h) { se[h] = 0.f; ss[h] = 0.f; }
#pragma unroll
    for (int it = 0; it < IT; ++it) {
      if (it * 64 >= n) break;
#pragma unroll
      for (int h = 0; h < Hh; ++h) {
        float ex = expf(lv[it][h] - mx[h]);  // inactive lanes: exp(-inf)=0
        se[h] += ex;
        ss[h] += ex * sjv[it];
      }
    }
    sedge = waveSum(sedge);
#pragma unroll
    for (int h = 0; h < Hh; ++h) {
      se[h] = waveSum(se[h]);
      ss[h] = waveSum(ss[h]);
    }
    if (lane == 0) {
      float acc = 0.f;
#pragma unroll
      for (int h = 0; h < Hh; ++h) {
        float nz = expf(-mx[h]);  // exp(0 - max) per non-edge cell
        float denom = se[h] + nz * ((float)Nn - (float)n);
        float numer = ss[h] + nz * (Ssum - sedge);
        acc += numer / denom;
      }
      out[i] = acc * (1.f / (float)Hh);
    }
  }
}

extern "C" void kernel_launch(void* const* d_in, const int* in_sizes, int n_in,
                              void* d_out, int out_size, void* d_ws, size_t ws_size,
                              hipStream_t stream) {
  const float* scores = (const float*)d_in[0];
  const float* emb    = (const float*)d_in[1];
  const float* attw   = (const float*)d_in[2];
  const int*   el     = (const int*)d_in[3];
  float* out = (float*)d_out;
  int E = in_sizes[3] / (Tt * 2);

  fused_kernel<<<NBLK, 256, 0, stream>>>(scores, emb, attw, el, E, out);
}

// Round 14
// 51.282 us; speedup vs baseline: 1.9558x; 1.9558x over previous
//
#include <hip/hip_runtime.h>

#define NEG_SLOPE_F 0.2f

static constexpr int Nn = 4096;   // nodes
static constexpr int Tt = 3;      // edge types
static constexpr int Dd = 16;     // emb dim
static constexpr int Hh = 4;      // heads
static constexpr int CAP = 256;   // max distinct neighbors per row (E[deg]≈96)
static constexpr int ROWS = 64;   // rows per block
static constexpr int NBLK = Nn / ROWS;  // 64 blocks
static constexpr int WPT = 128;   // bitmap words per (row,type): 4096/32
static constexpr int NT = 1024;   // threads per block (16 waves)
static constexpr int NW = NT / 64;

__device__ __forceinline__ float waveMax(float v) {
#pragma unroll
  for (int m = 1; m < 64; m <<= 1) v = fmaxf(v, __shfl_xor(v, m));
  return v;
}
__device__ __forceinline__ float waveSum(float v) {
#pragma unroll
  for (int m = 1; m < 64; m <<= 1) v += __shfl_xor(v, m);
  return v;
}

// Single kernel, zero cross-block deps. 64 fat blocks (1024 thr, 96KB LDS):
//   clear LDS bitmap -> brute-scan full edge list with 16 waves of TLP
//   (LDS atomicOr dedup, order-free -> deterministic) -> per-wave extraction
//   + analytic sparse softmax. Each CU ingests the 1.5MB list exactly once.
__global__ void __launch_bounds__(NT) fused_kernel(
    const float* __restrict__ scores, const float* __restrict__ emb,
    const float* __restrict__ attw, const int* __restrict__ el, int E,
    float* __restrict__ out) {
  __shared__ unsigned int bm[ROWS][Tt * WPT];  // 96 KB
  __shared__ unsigned short lst[NW][CAP];      // 8 KB, wave-private slices
  __shared__ float pvs[16];                    // c[h][t] (12) + Ssum
  __shared__ float rb[NW];

  int tid = threadIdx.x;
  int wid = tid >> 6, lane = tid & 63;
  int R0 = blockIdx.x * ROWS;

  // ---- clear the block's private bitmap ----
  unsigned int* bmf = &bm[0][0];
  for (int q = tid; q < ROWS * Tt * WPT; q += NT) bmf[q] = 0u;

  // ---- block-local sum(scores) (redundant per block; L2-hot 16 KB) ----
  {
    float s = 0.f;
    for (int j = tid; j < Nn; j += NT) s += scores[j];
    s = waveSum(s);
    if (lane == 0) rb[wid] = s;
  }
  __syncthreads();  // bitmap cleared + rb ready
  if (tid == 0) {
    float s = 0.f;
#pragma unroll
    for (int q = 0; q < NW; ++q) s += rb[q];
    pvs[12] = s;
  }
  if (tid < Hh * Tt) {
    int h = tid / Tt, t = tid % Tt;
    float c = 0.f;
#pragma unroll
    for (int d = 0; d < Dd; ++d)
      c += emb[t * Dd + d] * attw[h * (Dd + 2) + 1 + d];
    pvs[tid] = c;
  }

  // ---- brute scan of the full edge list (int4-vectorized, coalesced) ----
  int E4 = E >> 2;
  for (int t = 0; t < Tt; ++t) {
    const int4* s4 = (const int4*)(el + (size_t)(t * 2 + 0) * E);
    const int4* d4 = (const int4*)(el + (size_t)(t * 2 + 1) * E);
    for (int k = tid; k < E4; k += NT) {
      int4 a4 = s4[k], b4 = d4[k];
#pragma unroll
      for (int q = 0; q < 4; ++q) {
        unsigned int a =
            (unsigned int)(q == 0 ? a4.x : q == 1 ? a4.y : q == 2 ? a4.z : a4.w);
        unsigned int b =
            (unsigned int)(q == 0 ? b4.x : q == 1 ? b4.y : q == 2 ? b4.z : b4.w);
        unsigned int ra = a - (unsigned int)R0;
        if (ra < (unsigned int)ROWS)
          atomicOr(&bm[ra][t * WPT + (b >> 5)], 1u << (b & 31u));
        unsigned int rbx = b - (unsigned int)R0;
        if (rbx < (unsigned int)ROWS)
          atomicOr(&bm[rbx][t * WPT + (a >> 5)], 1u << (a & 31u));
      }
    }
    // generic tail (E % 4 != 0); no-op for E = 65536
    for (int e = E4 * 4 + tid; e < E; e += NT) {
      unsigned int a = (unsigned int)el[(size_t)(t * 2 + 0) * E + e];
      unsigned int b = (unsigned int)el[(size_t)(t * 2 + 1) * E + e];
      unsigned int ra = a - (unsigned int)R0;
      if (ra < (unsigned int)ROWS)
        atomicOr(&bm[ra][t * WPT + (b >> 5)], 1u << (b & 31u));
      unsigned int rbx = b - (unsigned int)R0;
      if (rbx < (unsigned int)ROWS)
        atomicOr(&bm[rbx][t * WPT + (a >> 5)], 1u << (a & 31u));
    }
  }
  __syncthreads();  // bitmap + pvs visible to row phase

  // ---- row phase: each of 16 waves processes 4 rows sequentially ----
  float wsrc[Hh], wtgt[Hh], c0[Hh], c1[Hh], c2[Hh];
#pragma unroll
  for (int h = 0; h < Hh; ++h) {
    wsrc[h] = attw[h * (Dd + 2) + 0];
    wtgt[h] = attw[h * (Dd + 2) + Dd + 1];
    c0[h] = pvs[h * 3 + 0];
    c1[h] = pvs[h * 3 + 1];
    c2[h] = pvs[h * 3 + 2];
  }
  float Ssum = pvs[12];

  constexpr int RPW = ROWS / NW;  // 4 rows per wave
  for (int rr = 0; rr < RPW; ++rr) {
    int lr = wid * RPW + rr;
    int i = R0 + lr;

    // canonical extraction (proven path), LDS-sourced
    unsigned int w[2][3];
#pragma unroll
    for (int p = 0; p < 2; ++p)
#pragma unroll
      for (int t = 0; t < 3; ++t) w[p][t] = bm[lr][t * WPT + p * 64 + lane];
    unsigned int orw[2];
    orw[0] = w[0][0] | w[0][1] | w[0][2];
    orw[1] = w[1][0] | w[1][1] | w[1][2];
    int c = __popc(orw[0]) + __popc(orw[1]);
    int off = c;
#pragma unroll
    for (int d = 1; d < 64; d <<= 1) {
      int tv = __shfl_up(off, d);
      if (lane >= d) off += tv;
    }
    int n = __shfl(off, 63);  // distinct neighbors of row i
    off -= c;                 // exclusive
    if (n > CAP) n = CAP;
    int idx = off;
#pragma unroll
    for (int p = 0; p < 2; ++p) {
      unsigned int o = orw[p];
      int jbase = (p * 64 + lane) * 32;
      while (o) {
        int b = __ffs(o) - 1;
        o &= o - 1;
        unsigned int m = ((w[p][0] >> b) & 1u) | (((w[p][1] >> b) & 1u) << 1) |
                         (((w[p][2] >> b) & 1u) << 2);
        if (idx < CAP) lst[wid][idx] = (unsigned short)((jbase + b) | (m << 12));
        ++idx;
      }
    }
    // lst[wid] produced+consumed by the same wave: no block barrier needed.

    float si = scores[i];
    constexpr int IT = CAP / 64;  // 4
    float lv[IT][Hh], sjv[IT];
    float mx[Hh];
#pragma unroll
    for (int h = 0; h < Hh; ++h) mx[h] = -INFINITY;
    float sedge = 0.f;

#pragma unroll
    for (int it = 0; it < IT; ++it) {
      if (it * 64 >= n) break;  // wave-uniform early-out
      int k = it * 64 + lane;
      bool act = k < n;
      unsigned int v = act ? (unsigned int)lst[wid][k] : 0u;
      int j = (int)(v & 0xFFFu);
      int m = act ? (int)(v >> 12) : 0;
      float sj = act ? scores[j] : 0.f;
      sjv[it] = sj;
      if (act) sedge += sj;
      float na = (float)__popc(m);
      float et0 = (m & 1) ? 1.f : 0.f;
      float et1 = (m & 2) ? 1.f : 0.f;
      float et2 = (m & 4) ? 1.f : 0.f;
#pragma unroll
      for (int h = 0; h < Hh; ++h) {
        float et = et0 * c0[h] + et1 * c1[h] + et2 * c2[h];
        float l = na * (wsrc[h] * si + wtgt[h] * sj) + et;
        l = (l >= 0.f) ? l : NEG_SLOPE_F * l;
        lv[it][h] = act ? l : -INFINITY;
        mx[h] = fmaxf(mx[h], lv[it][h]);
      }
    }

#pragma unroll
    for (int h = 0; h < Hh; ++h) {
      mx[h] = waveMax(mx[h]);
      if (n < Nn) mx[h] = fmaxf(mx[h], 0.f);  // non-edge logits are 0
    }

    float se[Hh], ss[Hh];
#pragma unroll
    for (int h = 0; h < Hh; ++h) { se[h] = 0.f; ss[h] = 0.f; }
#pragma unroll
    for (int it = 0; it < IT; ++it) {
      if (it * 64 >= n) break;
#pragma unroll
      for (int h = 0; h < Hh; ++h) {
        float ex = expf(lv[it][h] - mx[h]);  // inactive lanes: exp(-inf)=0
        se[h] += ex;
        ss[h] += ex * sjv[it];
      }
    }
    sedge = waveSum(sedge);
#pragma unroll
    for (int h = 0; h < Hh; ++h) {
      se[h] = waveSum(se[h]);
      ss[h] = waveSum(ss[h]);
    }
    if (lane == 0) {
      float acc = 0.f;
#pragma unroll
      for (int h = 0; h < Hh; ++h) {
        float nz = expf(-mx[h]);  // exp(0 - max) per non-edge cell
        float denom = se[h] + nz * ((float)Nn - (float)n);
        float numer = ss[h] + nz * (Ssum - sedge);
        acc += numer / denom;
      }
      out[i] = acc * (1.f / (float)Hh);
    }
  }
}

extern "C" void kernel_launch(void* const* d_in, const int* in_sizes, int n_in,
                              void* d_out, int out_size, void* d_ws, size_t ws_size,
                              hipStream_t stream) {
  const float* scores = (const float*)d_in[0];
  const float* emb    = (const float*)d_in[1];
  const float* attw   = (const float*)d_in[2];
  const int*   el     = (const int*)d_in[3];
  float* out = (float*)d_out;
  int E = in_sizes[3] / (Tt * 2);

  fused_kernel<<<NBLK, NT, 0, stream>>>(scores, emb, attw, el, E, out);
}

// Round 15
// 35.003 us; speedup vs baseline: 2.8653x; 1.4650x over previous
//
#include <hip/hip_runtime.h>

#define NEG_SLOPE_F 0.2f

static constexpr int Nn = 4096;   // nodes
static constexpr int Tt = 3;      // edge types
static constexpr int Dd = 16;     // emb dim
static constexpr int Hh = 4;      // heads
static constexpr int CAP = 256;   // max distinct neighbors per row (E[deg]≈96)
static constexpr int WPR = 128;   // 32-bit words per row per type (4096/32)

__device__ __forceinline__ float waveMax(float v) {
#pragma unroll
  for (int m = 1; m < 64; m <<= 1) v = fmaxf(v, __shfl_xor(v, m));
  return v;
}
__device__ __forceinline__ float waveSum(float v) {
#pragma unroll
  for (int m = 1; m < 64; m <<= 1) v += __shfl_xor(v, m);
  return v;
}

// ---- kernel 1: zero the 6 MB bitmap (wide grid-stride stores); block 0 also
// computes pv[0..11] = c[h][t] and pv[12] = sum(scores) ----
__global__ void clear_prep_kernel(uint4* __restrict__ bm4,
                                  const float* __restrict__ scores,
                                  const float* __restrict__ emb,
                                  const float* __restrict__ attw,
                                  float* __restrict__ pv) {
  const int total = Nn * 3 * WPR / 4;  // 393216 uint4
  uint4 z = make_uint4(0u, 0u, 0u, 0u);
  for (int k = blockIdx.x * 256 + threadIdx.x; k < total; k += gridDim.x * 256)
    bm4[k] = z;
  if (blockIdx.x == 0) {
    __shared__ float rb[4];
    int tid = threadIdx.x;
    float s = 0.f;
    for (int j = tid; j < Nn; j += 256) s += scores[j];
    s = waveSum(s);
    if ((tid & 63) == 0) rb[tid >> 6] = s;
    __syncthreads();
    if (tid == 0) pv[12] = rb[0] + rb[1] + rb[2] + rb[3];
    if (tid < Hh * Tt) {
      int h = tid / Tt, t = tid % Tt;
      float c = 0.f;
#pragma unroll
      for (int d = 0; d < Dd; ++d)
        c += emb[t * Dd + d] * attw[h * (Dd + 2) + 1 + d];
      pv[tid] = c;
    }
  }
}

// ---- kernel 2: fire-and-forget bit atomicOr, ONE atomic per thread ----
// (z-dim = direction) bitmap: word[(row*3 + t)*WPR + (col>>5)], bit = col&31
__global__ void or_kernel(const int* __restrict__ el,
                          unsigned int* __restrict__ bitmap, int E) {
  int e = blockIdx.x * blockDim.x + threadIdx.x;
  if (e >= E) return;
  int t = blockIdx.y;
  int dir = blockIdx.z;
  unsigned int a = (unsigned int)el[(t * 2 + dir) * E + e];
  unsigned int b = (unsigned int)el[(t * 2 + (1 - dir)) * E + e];
  atomicOr(&bitmap[(a * 3u + t) * WPR + (b >> 5)], 1u << (b & 31u));
}

// ---- kernel 3: one wave per row — extract packed (j|m<<12) pairs from the
// bitmap into wave-private LDS (no barrier needed), then softmax-aggregate ----
__launch_bounds__(256)
__global__ void row_kernel(const unsigned int* __restrict__ bitmap,
                           const float* __restrict__ scores,
                           const float* __restrict__ attw,
                           const float* __restrict__ pv,
                           float* __restrict__ out) {
  __shared__ unsigned short lst[4][CAP];  // 2 KiB, wave-private slices
  int wid = threadIdx.x >> 6, lane = threadIdx.x & 63;
  int i = blockIdx.x * 4 + wid;
  const unsigned int* bm = bitmap + (size_t)i * 3 * WPR;

  // read this row's 6 words per lane (2 word-blocks x 3 types), coalesced
  unsigned int w[2][3];
#pragma unroll
  for (int p = 0; p < 2; ++p)
#pragma unroll
    for (int t = 0; t < 3; ++t) w[p][t] = bm[t * WPR + p * 64 + lane];
  unsigned int orw[2];
  orw[0] = w[0][0] | w[0][1] | w[0][2];
  orw[1] = w[1][0] | w[1][1] | w[1][2];
  int c = __popc(orw[0]) + __popc(orw[1]);
  // inclusive wave scan -> per-lane output offsets
  int off = c;
#pragma unroll
  for (int d = 1; d < 64; d <<= 1) {
    int tv = __shfl_up(off, d);
    if (lane >= d) off += tv;
  }
  int n = __shfl(off, 63);  // row degree (distinct neighbors)
  off -= c;                 // exclusive
  if (n > CAP) n = CAP;
  int idx = off;
#pragma unroll
  for (int p = 0; p < 2; ++p) {
    unsigned int o = orw[p];
    int jbase = (p * 64 + lane) * 32;
    while (o) {
      int b = __ffs(o) - 1;
      o &= o - 1;
      unsigned int m = ((w[p][0] >> b) & 1u) | (((w[p][1] >> b) & 1u) << 1) |
                       (((w[p][2] >> b) & 1u) << 2);
      if (idx < CAP) lst[wid][idx] = (unsigned short)((jbase + b) | (m << 12));
      ++idx;
    }
  }
  // lst[wid] is produced and consumed by the same wave; compiler lgkmcnt
  // waits order the LDS RAW dependence — no block barrier needed.

  float si = scores[i];
  float wsrc[Hh], wtgt[Hh], c0[Hh], c1[Hh], c2[Hh];
#pragma unroll
  for (int h = 0; h < Hh; ++h) {
    wsrc[h] = attw[h * (Dd + 2) + 0];
    wtgt[h] = attw[h * (Dd + 2) + Dd + 1];
    c0[h] = pv[h * 3 + 0];
    c1[h] = pv[h * 3 + 1];
    c2[h] = pv[h * 3 + 2];
  }
  float Ssum = pv[12];

  constexpr int IT = CAP / 64;  // 4
  float lv[IT][Hh], sjv[IT];
  float mx[Hh];
#pragma unroll
  for (int h = 0; h < Hh; ++h) mx[h] = -INFINITY;
  float sedge = 0.f;

#pragma unroll
  for (int it = 0; it < IT; ++it) {
    if (it * 64 >= n) break;  // wave-uniform early-out
    int k = it * 64 + lane;
    bool act = k < n;
    unsigned int v = act ? (unsigned int)lst[wid][k] : 0u;
    int j = (int)(v & 0xFFFu);
    int m = act ? (int)(v >> 12) : 0;
    float sj = act ? scores[j] : 0.f;
    sjv[it] = sj;
    if (act) sedge += sj;
    float na = (float)__popc(m);
    float et0 = (m & 1) ? 1.f : 0.f;
    float et1 = (m & 2) ? 1.f : 0.f;
    float et2 = (m & 4) ? 1.f : 0.f;
#pragma unroll
    for (int h = 0; h < Hh; ++h) {
      float et = et0 * c0[h] + et1 * c1[h] + et2 * c2[h];
      float l = na * (wsrc[h] * si + wtgt[h] * sj) + et;
      l = (l >= 0.f) ? l : NEG_SLOPE_F * l;
      lv[it][h] = act ? l : -INFINITY;
      mx[h] = fmaxf(mx[h], lv[it][h]);
    }
  }

#pragma unroll
  for (int h = 0; h < Hh; ++h) {
    mx[h] = waveMax(mx[h]);
    if (n < Nn) mx[h] = fmaxf(mx[h], 0.f);  // non-edge cells contribute logit 0
  }

  float se[Hh], ss[Hh];
#pragma unroll
  for (int h = 0; h < Hh; ++h) { se[h] = 0.f; ss[h] = 0.f; }
#pragma unroll
  for (int it = 0; it < IT; ++it) {
    if (it * 64 >= n) break;
#pragma unroll
    for (int h = 0; h < Hh; ++h) {
      float ex = expf(lv[it][h] - mx[h]);  // inactive lanes: exp(-inf)=0
      se[h] += ex;
      ss[h] += ex * sjv[it];
    }
  }
  sedge = waveSum(sedge);
#pragma unroll
  for (int h = 0; h < Hh; ++h) {
    se[h] = waveSum(se[h]);
    ss[h] = waveSum(ss[h]);
  }
  if (lane == 0) {
    float acc = 0.f;
#pragma unroll
    for (int h = 0; h < Hh; ++h) {
      float nz = expf(-mx[h]);  // exp(0 - max) for every non-edge cell
      float denom = se[h] + nz * ((float)Nn - (float)n);
      float numer = ss[h] + nz * (Ssum - sedge);
      acc += numer / denom;
    }
    out[i] = acc * (1.f / (float)Hh);
  }
}

extern "C" void kernel_launch(void* const* d_in, const int* in_sizes, int n_in,
                              void* d_out, int out_size, void* d_ws, size_t ws_size,
                              hipStream_t stream) {
  const float* scores = (const float*)d_in[0];
  const float* emb    = (const float*)d_in[1];
  const float* attw   = (const float*)d_in[2];
  const int*   el     = (const int*)d_in[3];
  float* out = (float*)d_out;
  int E = in_sizes[3] / (Tt * 2);

  // ws layout: [bitmap 6MB][pv 64B]
  size_t bm_bytes = (size_t)Nn * 3 * WPR * 4;  // 6 MiB
  unsigned int* bitmap = (unsigned int*)d_ws;
  float* pv = (float*)((char*)d_ws + bm_bytes);

  clear_prep_kernel<<<768, 256, 0, stream>>>((uint4*)d_ws, scores, emb, attw, pv);
  or_kernel<<<dim3((E + 255) / 256, Tt, 2), 256, 0, stream>>>(el, bitmap, E);
  row_kernel<<<Nn / 4, 256, 0, stream>>>(bitmap, scores, attw, pv, out);
}